// Round 4
// baseline (1846.688 us; speedup 1.0000x reference)
//
#include <hip/hip_runtime.h>

#define NB 32
#define NT 8192
#define NC 64
#define MD 64
#define NLAG 129      // 2*MD+1
#define TC 256        // time chunk per block
#define RT 16         // register time tile
#define NCHUNK (NT / TC)

// Sliding-FIR body. Wave handles lags d = D0 + i, i in [0,33); acc[32] is
// garbage (dropped later) for w<3 so the inner loops need no lag guard.
// Structure: issue ALL 64 loads for the step into registers first (one
// waitcnt), then the 528-FMA block — breaks the load->use serialization
// that left round-2 at VALUBusy=13% / VGPR=64.
template<bool CHECKED>
__device__ __forceinline__ void corr_body(const float* __restrict__ Ab,
                                          const float* __restrict__ Bb,
                                          int t_start, int D0, int w,
                                          float acc[33], float& sqa, float& sqb)
{
    // unroll 1: keep one body copy (~5KB) in the 32KB I-cache; latency of the
    // single per-step waitcnt is covered by 4 waves/SIMD TLP
    #pragma unroll 1
    for (int t0 = t_start; t0 < t_start + TC; t0 += RT) {
        float bv[RT];
        float av[RT + 32];

        // ---- load phase: 64 independent loads, no uses in between ----
        #pragma unroll
        for (int j = 0; j < RT; ++j) bv[j] = Bb[(t0 + j) * NC];
        #pragma unroll
        for (int u = 0; u < RT + 32; ++u) {
            const int s = t0 + D0 + u;
            if (CHECKED) {
                av[u] = ((unsigned)s < (unsigned)NT) ? Ab[s * NC] : 0.0f;
            } else {
                av[u] = Ab[s * NC];
            }
        }

        // ---- norm partials from already-loaded registers ----
        if (w == 0) {
            #pragma unroll
            for (int j = 0; j < RT; ++j) sqb = fmaf(bv[j], bv[j], sqb);
        } else if (w == 1) {
            // for w==1, D0 = -32, so av[j+32] == a[t0+j] (always in range,
            // never zero-clamped, even in CHECKED chunks)
            #pragma unroll
            for (int j = 0; j < RT; ++j) sqa = fmaf(av[j + 32], av[j + 32], sqa);
        }

        // ---- FMA phase: 528 FMAs, 33 independent chains, all operands resident ----
        #pragma unroll
        for (int u = 0; u < RT + 32; ++u) {
            #pragma unroll
            for (int i = 0; i < 33; ++i) {
                const int j = u - i;              // compile-time per instance
                if (j >= 0 && j < RT)
                    acc[i] = fmaf(av[u], bv[j], acc[i]);
            }
        }
    }
}

__global__ __launch_bounds__(256, 4)
void corr_kernel(const float* __restrict__ A,
                 const float* __restrict__ Bm,
                 float* __restrict__ out,   // [NB][NLAG][NC] raw corr sums (pre-zeroed)
                 float* __restrict__ sa,    // [NB][NC] sum a^2 (pre-zeroed)
                 float* __restrict__ sb)    // [NB][NC] sum b^2 (pre-zeroed)
{
    const int lane  = threadIdx.x & 63;
    const int w     = threadIdx.x >> 6;
    const int bidx  = blockIdx.x / NCHUNK;
    const int chunk = blockIdx.x % NCHUNK;
    const int t_start = chunk * TC;

    const float* Ab = A  + ((size_t)bidx * NT) * NC + lane;
    const float* Bb = Bm + ((size_t)bidx * NT) * NC + lane;
    const int D0 = -MD + w * 32;   // wave's first lag

    float acc[33];
    #pragma unroll
    for (int i = 0; i < 33; ++i) acc[i] = 0.0f;
    float sqa = 0.0f, sqb = 0.0f;

    if (chunk == 0 || chunk == NCHUNK - 1)
        corr_body<true >(Ab, Bb, t_start, D0, w, acc, sqa, sqb);
    else
        corr_body<false>(Ab, Bb, t_start, D0, w, acc, sqa, sqb);

    // epilogue: k = d + MD = w*32 + i; waves own disjoint lag bands,
    // atomics only contend across the 32 time-chunks of a batch
    float* outb = out + ((size_t)bidx * NLAG + w * 32) * NC + lane;
    #pragma unroll
    for (int i = 0; i < 33; ++i) {
        if (i < 32 || w == 3) atomicAdd(&outb[i * NC], acc[i]);
    }
    if (w == 0)      atomicAdd(&sb[bidx * NC + lane], sqb);
    else if (w == 1) atomicAdd(&sa[bidx * NC + lane], sqa);
}

__global__ void scale_kernel(float* __restrict__ out,
                             const float* __restrict__ sa,
                             const float* __restrict__ sb)
{
    const int idx = blockIdx.x * blockDim.x + threadIdx.x;
    if (idx >= NB * NLAG * NC) return;
    const int c = idx & (NC - 1);
    const int b = idx / (NLAG * NC);
    // reference: x * rsqrt(max(sum_sq, eps)) for each input, then product
    const float inv = rsqrtf(fmaxf(sa[b * NC + c], 1e-12f)) *
                      rsqrtf(fmaxf(sb[b * NC + c], 1e-12f));
    out[idx] = out[idx] * inv;
}

extern "C" void kernel_launch(void* const* d_in, const int* in_sizes, int n_in,
                              void* d_out, int out_size, void* d_ws, size_t ws_size,
                              hipStream_t stream)
{
    const float* A  = (const float*)d_in[0];
    const float* Bm = (const float*)d_in[1];
    float* out = (float*)d_out;
    float* sa  = (float*)d_ws;            // [NB*NC]
    float* sb  = sa + NB * NC;            // [NB*NC]

    // d_out / d_ws are poisoned 0xAA before every timed launch
    hipMemsetAsync(d_out, 0, (size_t)out_size * sizeof(float), stream);
    hipMemsetAsync(d_ws, 0, (size_t)(2 * NB * NC) * sizeof(float), stream);

    corr_kernel<<<dim3(NB * NCHUNK), dim3(256), 0, stream>>>(A, Bm, out, sa, sb);

    const int n_out = NB * NLAG * NC;
    scale_kernel<<<dim3((n_out + 255) / 256), dim3(256), 0, stream>>>(out, sa, sb);
}

// Round 6
// 386.945 us; speedup vs baseline: 4.7725x; 4.7725x over previous
//
#include <hip/hip_runtime.h>

#define NB 32
#define NT 8192
#define NC 64
#define MD 64
#define NLAG 129      // 2*MD+1
#define TC 256        // time chunk per block
#define RT 16         // register time tile
#define PF 16         // a-value prefetch queue depth
#define NCHUNK (NT / TC)

// Sliding-FIR body. Wave handles lags d = D0 + i, i in [0,33); acc[32] is
// garbage (dropped later) for w<3 so the inner loops need no lag guard.
//
// Lessons encoded here:
//  - r2: loads scheduled next to uses (VGPR=64, VALUBusy=13%) -> latency-bound.
//  - r4: av[48] upfront -> alloca demoted to scratch (+750MB HBM spill).
//  - r5: PF=16 rolling queue (65 total alloca floats, promotes) + per-group
//    sched_barrier(0) so the backend scheduler CANNOT re-collapse the
//    pipeline: each load issues PF groups (~350+ VALU cyc) before its use.
template<bool CHECKED>
__device__ __forceinline__ void corr_body(const float* __restrict__ Ab,
                                          const float* __restrict__ Bb,
                                          int t_start, int D0, int w,
                                          float acc[33], float& sqa, float& sqb)
{
    // unroll 1: keep one body copy (~6KB) in the 32KB I-cache
    #pragma unroll 1
    for (int t0 = t_start; t0 < t_start + TC; t0 += RT) {
        float bv[RT];
        float ap[PF];

        #pragma unroll
        for (int j = 0; j < RT; ++j) bv[j] = Bb[(t0 + j) * NC];

        // prologue: fill the a-queue for u = 0..PF-1
        #pragma unroll
        for (int u = 0; u < PF; ++u) {
            const int s = t0 + D0 + u;
            if (CHECKED) {
                ap[u] = ((unsigned)s < (unsigned)NT) ? Ab[s * NC] : 0.0f;
            } else {
                ap[u] = Ab[s * NC];
            }
        }

        if (w == 0) {
            #pragma unroll
            for (int j = 0; j < RT; ++j) sqb = fmaf(bv[j], bv[j], sqb);
        }

        // steady state: consume ap[u%PF], re-issue load for u+PF into the
        // freed slot. All queue indices compile-time after full unroll.
        // sched_barrier(0) per group pins program order: loads stay ~PF
        // groups ahead of their consuming FMAs (counted-vmcnt pipeline).
        #pragma unroll
        for (int u = 0; u < RT + 32; ++u) {
            const float av = ap[u % PF];
            if (u + PF < RT + 32) {
                const int s = t0 + D0 + u + PF;
                if (CHECKED) {
                    ap[u % PF] = ((unsigned)s < (unsigned)NT) ? Ab[s * NC] : 0.0f;
                } else {
                    ap[u % PF] = Ab[s * NC];
                }
            }
            // w==1 (D0=-32): u>=32 -> av == a[t0+(u-32)], always in range,
            // never zero-clamped, even in CHECKED chunks -> free sum(a^2)
            if (w == 1 && u >= 32) sqa = fmaf(av, av, sqa);

            #pragma unroll
            for (int i = 0; i < 33; ++i) {
                const int j = u - i;              // compile-time per instance
                if (j >= 0 && j < RT)
                    acc[i] = fmaf(av, bv[j], acc[i]);
            }
            __builtin_amdgcn_sched_barrier(0);
        }
    }
}

__global__ __launch_bounds__(256, 4)
void corr_kernel(const float* __restrict__ A,
                 const float* __restrict__ Bm,
                 float* __restrict__ out,   // [NB][NLAG][NC] raw corr sums (pre-zeroed)
                 float* __restrict__ sa,    // [NB][NC] sum a^2 (pre-zeroed)
                 float* __restrict__ sb)    // [NB][NC] sum b^2 (pre-zeroed)
{
    const int lane  = threadIdx.x & 63;
    const int w     = threadIdx.x >> 6;
    const int bidx  = blockIdx.x / NCHUNK;
    const int chunk = blockIdx.x % NCHUNK;
    const int t_start = chunk * TC;

    const float* Ab = A  + ((size_t)bidx * NT) * NC + lane;
    const float* Bb = Bm + ((size_t)bidx * NT) * NC + lane;
    const int D0 = -MD + w * 32;   // wave's first lag

    float acc[33];
    #pragma unroll
    for (int i = 0; i < 33; ++i) acc[i] = 0.0f;
    float sqa = 0.0f, sqb = 0.0f;

    if (chunk == 0 || chunk == NCHUNK - 1)
        corr_body<true >(Ab, Bb, t_start, D0, w, acc, sqa, sqb);
    else
        corr_body<false>(Ab, Bb, t_start, D0, w, acc, sqa, sqb);

    // epilogue: k = d + MD = w*32 + i; waves own disjoint lag bands,
    // atomics only contend across the 32 time-chunks of a batch
    float* outb = out + ((size_t)bidx * NLAG + w * 32) * NC + lane;
    #pragma unroll
    for (int i = 0; i < 33; ++i) {
        if (i < 32 || w == 3) atomicAdd(&outb[i * NC], acc[i]);
    }
    if (w == 0)      atomicAdd(&sb[bidx * NC + lane], sqb);
    else if (w == 1) atomicAdd(&sa[bidx * NC + lane], sqa);
}

__global__ void scale_kernel(float* __restrict__ out,
                             const float* __restrict__ sa,
                             const float* __restrict__ sb)
{
    const int idx = blockIdx.x * blockDim.x + threadIdx.x;
    if (idx >= NB * NLAG * NC) return;
    const int c = idx & (NC - 1);
    const int b = idx / (NLAG * NC);
    // reference: x * rsqrt(max(sum_sq, eps)) for each input, then product
    const float inv = rsqrtf(fmaxf(sa[b * NC + c], 1e-12f)) *
                      rsqrtf(fmaxf(sb[b * NC + c], 1e-12f));
    out[idx] = out[idx] * inv;
}

extern "C" void kernel_launch(void* const* d_in, const int* in_sizes, int n_in,
                              void* d_out, int out_size, void* d_ws, size_t ws_size,
                              hipStream_t stream)
{
    const float* A  = (const float*)d_in[0];
    const float* Bm = (const float*)d_in[1];
    float* out = (float*)d_out;
    float* sa  = (float*)d_ws;            // [NB*NC]
    float* sb  = sa + NB * NC;            // [NB*NC]

    // d_out / d_ws are poisoned 0xAA before every timed launch
    hipMemsetAsync(d_out, 0, (size_t)out_size * sizeof(float), stream);
    hipMemsetAsync(d_ws, 0, (size_t)(2 * NB * NC) * sizeof(float), stream);

    corr_kernel<<<dim3(NB * NCHUNK), dim3(256), 0, stream>>>(A, Bm, out, sa, sb);

    const int n_out = NB * NLAG * NC;
    scale_kernel<<<dim3((n_out + 255) / 256), dim3(256), 0, stream>>>(out, sa, sb);
}